// Round 10
// baseline (361.630 us; speedup 1.0000x reference)
//
#include <hip/hip_runtime.h>
#include <math.h>

typedef float  f32x4  __attribute__((ext_vector_type(4)));
typedef short  bf16x8 __attribute__((ext_vector_type(8)));
typedef unsigned short u16;

__device__ __forceinline__ u16 f2b(float f) {
  union { float f; unsigned u; } v; v.f = f;
  unsigned r = v.u + 0x7FFFu + ((v.u >> 16) & 1u);
  return (u16)(r >> 16);
}
__device__ __forceinline__ float b2f(u16 h) {
  union { unsigned u; float f; } v; v.u = ((unsigned)h) << 16;
  return v.f;
}

// async global->LDS, 16B per lane; dest = wave-uniform base + lane*16
__device__ __forceinline__ void gl_lds16(const u16* g, u16* l) {
  __builtin_amdgcn_global_load_lds(
      (const __attribute__((address_space(1))) unsigned*)g,
      (__attribute__((address_space(3))) unsigned*)l, 16, 0, 0);
}

// ---------------- fp32 -> bf16 conversion / packing ----------------
__global__ __launch_bounds__(256) void convert_kernel(
    const float* __restrict__ x,  const float* __restrict__ Wq,
    const float* __restrict__ Wk, const float* __restrict__ Wv,
    const float* __restrict__ Wo, const float* __restrict__ bq,
    const float* __restrict__ bk, const float* __restrict__ bv,
    u16* __restrict__ xb, u16* __restrict__ Wcat, u16* __restrict__ Wob,
    float* __restrict__ bcat)
{
  long i = ((long)blockIdx.x * 256 + threadIdx.x) * 4;
  if (i < 10485760L) {
    const float* src; u16* dst; long o;
    if (i < 4194304L)      { src = x;  dst = xb;             o = i; }
    else if (i < 6291456L) { src = Wq; dst = Wcat;           o = i - 4194304L; }
    else if (i < 8388608L) { src = Wk; dst = Wcat + 2097152; o = i - 6291456L; }
    else if (i < 9437184L) { src = Wv; dst = Wcat + 4194304; o = i - 8388608L; }
    else                   { src = Wo; dst = Wob;            o = i - 9437184L; }
    float4 v = *(const float4*)(src + o);
    union { u16 h[4]; uint2 u2; } p;
    p.h[0] = f2b(v.x); p.h[1] = f2b(v.y); p.h[2] = f2b(v.z); p.h[3] = f2b(v.w);
    *(uint2*)(dst + o) = p.u2;
  } else if (i < 10490880L) {
    long j = i - 10485760L;
    const float* src; long o;
    if (j < 2048)      { src = bq; o = j; }
    else if (j < 4096) { src = bk; o = j - 2048; }
    else               { src = bv; o = j - 4096; }
    *(float4*)(bcat + j) = *(const float4*)(src + o);
  }
}

// ---------------- RoPE cos/sin table: [s][i], i=0..31 ----------------
__global__ __launch_bounds__(256) void rope_table(
    float* __restrict__ ctab, float* __restrict__ stab)
{
  int idx = blockIdx.x * 256 + threadIdx.x;   // 0..32767
  int s = idx >> 5, i = idx & 31;
  float freq = expf(-(float)i * (9.210340371976184f / 32.f));  // 10000^(-i/32)
  float ang = (float)s * freq;
  ctab[idx] = cosf(ang);
  stab[idx] = sinf(ang);
}

// ---------------- MFMA NT GEMM, m97 structure (unchanged) ----------------
template<int EPI>
__global__ __launch_bounds__(256) void gemm_nt(
    const u16* __restrict__ A, const u16* __restrict__ Bw,
    const float* __restrict__ bias, float* __restrict__ outF,
    u16* __restrict__ q1t, u16* __restrict__ q2t,
    u16* __restrict__ k1t, u16* __restrict__ k2t, u16* __restrict__ vtT,
    const float* __restrict__ ctab, const float* __restrict__ stab,
    int N)
{
  const int K = 1024;
  __shared__ u16 As[128 * 32];
  __shared__ u16 Bs[128 * 32];
  int tid  = threadIdx.x;
  int lane = tid & 63, wave = tid >> 6;
  int wm = wave >> 1, wn = wave & 1;
  int m0 = blockIdx.y * 128, n0 = blockIdx.x * 128;
  int fr = lane & 15, hi = lane >> 4;

  int c0 = wave * 128 + lane;
  int c1 = c0 + 64;
  int r0 = c0 >> 2, q0_ = c0 & 3;
  int r1 = c1 >> 2, q1_ = c1 & 3;
  u16* asb0 = &As[wave * 1024];
  u16* asb1 = &As[wave * 1024 + 512];
  u16* bsb0 = &Bs[wave * 1024];
  u16* bsb1 = &Bs[wave * 1024 + 512];
  const u16* ag0 = A  + (size_t)(m0 + r0) * K + q0_ * 8;
  const u16* ag1 = A  + (size_t)(m0 + r1) * K + q1_ * 8;
  const u16* bg0 = Bw + (size_t)(n0 + r0) * K + q0_ * 8;
  const u16* bg1 = Bw + (size_t)(n0 + r1) * K + q1_ * 8;

  f32x4 acc[4][4];
#pragma unroll
  for (int i = 0; i < 4; ++i)
#pragma unroll
    for (int j = 0; j < 4; ++j) acc[i][j] = 0.0f;

  for (int kk0 = 0; kk0 < K; kk0 += 32) {
    __syncthreads();
    gl_lds16(ag0 + kk0, asb0);
    gl_lds16(ag1 + kk0, asb1);
    gl_lds16(bg0 + kk0, bsb0);
    gl_lds16(bg1 + kk0, bsb1);
    __syncthreads();
    bf16x8 af[4], bfv[4];
#pragma unroll
    for (int f = 0; f < 4; ++f) {
      af[f]  = *(const bf16x8*)&As[(wm * 64 + f * 16 + fr) * 32 + hi * 8];
      bfv[f] = *(const bf16x8*)&Bs[(wn * 64 + f * 16 + fr) * 32 + hi * 8];
    }
#pragma unroll
    for (int i = 0; i < 4; ++i)
#pragma unroll
      for (int j = 0; j < 4; ++j)
        acc[i][j] = __builtin_amdgcn_mfma_f32_16x16x32_bf16(af[i], bfv[j], acc[i][j], 0, 0, 0);
  }

  int rg = lane >> 4;
  if (EPI == 0) {
    if (n0 < 4096) {
      u16* dst; int base;
      if (n0 < 1024)      { dst = q1t; base = 0; }
      else if (n0 < 2048) { dst = q2t; base = 1024; }
      else if (n0 < 3072) { dst = k1t; base = 2048; }
      else                { dst = k2t; base = 3072; }
      float qs = (n0 < 2048) ? 0.18033688011112042f : 1.0f;   // 0.125*log2e
#pragma unroll
      for (int i = 0; i < 4; ++i) {
#pragma unroll
        for (int e = 0; e < 4; ++e) {
          int m = m0 + wm * 64 + i * 16 + rg * 4 + e;
          int b = m >> 10, s = m & 1023;
#pragma unroll
          for (int j = 0; j < 2; ++j) {
            int n_lo = n0 + wn * 64 + j * 16 + fr;
            int feat = n_lo - base;
            int h = feat >> 6, dh = feat & 63;   // dh < 32
            float a1 = acc[i][j][e]     + bias[n_lo];
            float a2 = acc[i][j + 2][e] + bias[n_lo + 32];
            float cs = ctab[s * 32 + dh], sn = stab[s * 32 + dh];
            size_t rowb = ((size_t)(b * 16 + h) * 1024 + s) * 64;
            dst[rowb + dh]      = f2b((a1 * cs - a2 * sn) * qs);
            dst[rowb + dh + 32] = f2b((a1 * sn + a2 * cs) * qs);
          }
        }
      }
    } else {
      // v tensor: TRANSPOSED store [bh][dh][s]
#pragma unroll
      for (int i = 0; i < 4; ++i) {
        int mbase = m0 + wm * 64 + i * 16 + rg * 4;
        int b = mbase >> 10, s0 = mbase & 1023;
#pragma unroll
        for (int j = 0; j < 4; ++j) {
          int n = n0 + wn * 64 + j * 16 + fr;
          int feat = n - 4096;
          int h = feat >> 6, dh = feat & 63;
          float bv = bias[n];
          union { u16 hh[4]; uint2 u2; } p;
#pragma unroll
          for (int e = 0; e < 4; ++e) p.hh[e] = f2b(acc[i][j][e] + bv);
          *(uint2*)&vtT[((size_t)(b * 16 + h) * 64 + dh) * 1024 + s0] = p.u2;
        }
      }
    }
  } else {
#pragma unroll
    for (int i = 0; i < 4; ++i)
#pragma unroll
      for (int j = 0; j < 4; ++j)
#pragma unroll
        for (int e = 0; e < 4; ++e) {
          int m = m0 + wm * 64 + i * 16 + rg * 4 + e;
          int n = n0 + wn * 64 + j * 16 + fr;
          outF[(size_t)m * N + n] = acc[i][j][e] + bias[n];
        }
  }
}

// ---------------- logL scan (base-2) ----------------
__global__ __launch_bounds__(1024) void scan_logl(
    const float* __restrict__ a, float* __restrict__ logL)
{
  __shared__ float sh[1024];
  int b = blockIdx.x, t = threadIdx.x;
  float v = (t == 0) ? 0.f : log2f(a[b * 1023 + t - 1]);
  sh[t] = v;
  __syncthreads();
  for (int off = 1; off < 1024; off <<= 1) {
    float add = (t >= off) ? sh[t - off] : 0.f;
    __syncthreads();
    sh[t] += add;
    __syncthreads();
  }
  logL[b * 1024 + t] = sh[t];
}

// ---------------- fused MFMA attention v5 ----------------
// = round-8 staged structure (best measured: 88us) + XCD-grouped block swizzle
// (proven FETCH 106->21MB in r9) + T14 prefetch: next tile's 6 K/V global loads
// issued right after the stage-write, latency hides under QK^T+exp+PV.
__global__ __launch_bounds__(256, 4) void attn_fused(
    const u16* __restrict__ q1t, const u16* __restrict__ q2t,
    const u16* __restrict__ k1t, const u16* __restrict__ k2t,
    const u16* __restrict__ vtT,
    const float* __restrict__ logL, const float* __restrict__ lamp,
    float* __restrict__ ctx)
{
  __shared__ u16 K1s[64][72];   // K1 during QK^T, P1 during PV
  __shared__ u16 K2s[64][72];   // K2 during QK^T, P2 during PV
  __shared__ u16 Vts[64][72];   // V^T [dh][k], k-blocks XOR-swizzled by (dh>>3)&7
  __shared__ float lred1[2][2][32];
  __shared__ float lred2[2][2][32];

  int tid  = threadIdx.x;
  int lane = tid & 63, wave = tid >> 6;
  int wm = wave >> 1, wn = wave & 1;
  int id = blockIdx.x;
  int bh = (id & 7) * 8 + (id >> 7);        // XCD-grouped: 8 bh per XCD (L2-fit)
  int q0 = ((id >> 3) & 15) * 64;
  int b = bh >> 4;
  int fr = lane & 15, hi = lane >> 4;

  bf16x8 qf1[2][2], qf2[2][2];
#pragma unroll
  for (int i = 0; i < 2; ++i)
#pragma unroll
    for (int ks = 0; ks < 2; ++ks) {
      size_t off = ((size_t)bh * 1024 + q0 + wm * 32 + i * 16 + fr) * 64 + ks * 32 + hi * 8;
      qf1[i][ks] = *(const bf16x8*)(q1t + off);
      qf2[i][ks] = *(const bf16x8*)(q2t + off);
    }
  float Lq[2][4];
#pragma unroll
  for (int i = 0; i < 2; ++i)
#pragma unroll
    for (int r = 0; r < 4; ++r)
      Lq[i][r] = logL[b * 1024 + q0 + wm * 32 + i * 16 + hi * 4 + r];

  float lacc1[2][4], lacc2[2][4];
  f32x4 U1[2][2], U2[2][2];
#pragma unroll
  for (int i = 0; i < 2; ++i)
#pragma unroll
    for (int r = 0; r < 4; ++r) { lacc1[i][r] = 0.f; lacc2[i][r] = 0.f; }
#pragma unroll
  for (int i = 0; i < 2; ++i)
#pragma unroll
    for (int j = 0; j < 2; ++j) { U1[i][j] = 0.f; U2[i][j] = 0.f; }

  int sr = tid >> 2, sc0 = (tid & 3) * 16;
  int swz = (sr >> 3) & 7;
  int blk0 = ((sc0 >> 3) ^ swz) << 3;
  int blk1 = (((sc0 >> 3) + 1) ^ swz) << 3;

  // LDS byte addresses for packed P writes (row wm*32+hi*4, col wn*32+fr)
  unsigned a1base = (unsigned)(size_t)&K1s[wm * 32 + hi * 4][wn * 32 + fr];
  unsigned a2base = (unsigned)(size_t)&K2s[wm * 32 + hi * 4][wn * 32 + fr];

  // staging global bases
  const u16* kg1 = k1t + ((size_t)bh * 1024 + sr) * 64 + sc0;   // + kt*64*64
  const u16* kg2 = k2t + ((size_t)bh * 1024 + sr) * 64 + sc0;
  const u16* vgT = vtT + (size_t)bh * 65536 + (size_t)sr * 1024 + sc0;  // + kt*64

  // prologue: prefetch tile 0 into regs
  bf16x8 ra0 = *(const bf16x8*)(kg1),     ra1 = *(const bf16x8*)(kg1 + 8);
  bf16x8 rb0 = *(const bf16x8*)(kg2),     rb1 = *(const bf16x8*)(kg2 + 8);
  bf16x8 rv0 = *(const bf16x8*)(vgT),     rv1 = *(const bf16x8*)(vgT + 8);

  for (int kt = 0; kt < 16; ++kt) {
    __syncthreads();   // (1) prev PV reads done -> LDS reusable
    // ---- write prefetched regs to LDS ----
    *(bf16x8*)&K1s[sr][sc0]     = ra0;  *(bf16x8*)&K1s[sr][sc0 + 8] = ra1;
    *(bf16x8*)&K2s[sr][sc0]     = rb0;  *(bf16x8*)&K2s[sr][sc0 + 8] = rb1;
    *(bf16x8*)&Vts[sr][blk0]    = rv0;  *(bf16x8*)&Vts[sr][blk1]    = rv1;
    float Ltl[2];
#pragma unroll
    for (int j = 0; j < 2; ++j) Ltl[j] = logL[b * 1024 + kt * 64 + wn * 32 + j * 16 + fr];
    // ---- issue next tile's loads (latency hides under QK^T+exp+PV) ----
    if (kt < 15) {
      size_t ko = (size_t)(kt + 1) * 64 * 64;
      size_t vo = (size_t)(kt + 1) * 64;
      ra0 = *(const bf16x8*)(kg1 + ko);     ra1 = *(const bf16x8*)(kg1 + ko + 8);
      rb0 = *(const bf16x8*)(kg2 + ko);     rb1 = *(const bf16x8*)(kg2 + ko + 8);
      rv0 = *(const bf16x8*)(vgT + vo);     rv1 = *(const bf16x8*)(vgT + vo + 8);
    }
    __syncthreads();   // (2) stage complete

    // ---- QK^T ----
    f32x4 S1[2][2], S2[2][2];
#pragma unroll
    for (int i = 0; i < 2; ++i)
#pragma unroll
      for (int j = 0; j < 2; ++j) { S1[i][j] = 0.f; S2[i][j] = 0.f; }
    __builtin_amdgcn_s_setprio(1);
#pragma unroll
    for (int ks = 0; ks < 2; ++ks) {
      bf16x8 kf1[2], kf2[2];
#pragma unroll
      for (int j = 0; j < 2; ++j) {
        kf1[j] = *(const bf16x8*)&K1s[wn * 32 + j * 16 + fr][ks * 32 + hi * 8];
        kf2[j] = *(const bf16x8*)&K2s[wn * 32 + j * 16 + fr][ks * 32 + hi * 8];
      }
#pragma unroll
      for (int i = 0; i < 2; ++i)
#pragma unroll
        for (int j = 0; j < 2; ++j) {
          S1[i][j] = __builtin_amdgcn_mfma_f32_16x16x32_bf16(qf1[i][ks], kf1[j], S1[i][j], 0, 0, 0);
          S2[i][j] = __builtin_amdgcn_mfma_f32_16x16x32_bf16(qf2[i][ks], kf2[j], S2[i][j], 0, 0, 0);
        }
    }
    __builtin_amdgcn_s_setprio(0);
    __syncthreads();   // (3) all K reads done -> K-space reusable as P

    // ---- exponentials (log2 domain) + packed P write ----
#pragma unroll
    for (int i = 0; i < 2; ++i) {
#pragma unroll
      for (int r = 0; r < 4; ++r) {
        float lq = Lq[i][r];
        float e1j[2], e2j[2], p1j[2], p2j[2];
#pragma unroll
        for (int j = 0; j < 2; ++j) {
          float nd = -fabsf(Ltl[j] - lq);
          float t1, t2, ec;
          asm("v_exp_f32 %0, %1" : "=v"(t1) : "v"(S1[i][j][r]));
          asm("v_exp_f32 %0, %1" : "=v"(t2) : "v"(S2[i][j][r]));
          asm("v_exp_f32 %0, %1" : "=v"(ec) : "v"(nd));
          e1j[j] = t1; e2j[j] = t2;
          p1j[j] = t1 * ec; p2j[j] = t2 * ec;
        }
        lacc1[i][r] += e1j[0] + e1j[1];
        lacc2[i][r] += e2j[0] + e2j[1];
        unsigned off = (unsigned)((i * 16 + r) * 144);
        unsigned ad1 = a1base + off, ad2 = a2base + off;
        unsigned pk1, pk2;
        asm("v_cvt_pk_bf16_f32 %0, %1, %2" : "=v"(pk1) : "v"(p1j[0]), "v"(p1j[1]));
        asm("v_cvt_pk_bf16_f32 %0, %1, %2" : "=v"(pk2) : "v"(p2j[0]), "v"(p2j[1]));
        asm volatile("ds_write_b16 %0, %1\n\tds_write_b16_d16_hi %0, %1 offset:32"
                     :: "v"(ad1), "v"(pk1) : "memory");
        asm volatile("ds_write_b16 %0, %1\n\tds_write_b16_d16_hi %0, %1 offset:32"
                     :: "v"(ad2), "v"(pk2) : "memory");
      }
    }
    __syncthreads();   // (4) P complete

    // ---- PV: U += P * V (P in K1s/K2s, V^T in Vts) ----
    __builtin_amdgcn_s_setprio(1);
#pragma unroll
    for (int ks = 0; ks < 2; ++ks) {
      bf16x8 pa1[2], pa2[2], vb[2];
#pragma unroll
      for (int i = 0; i < 2; ++i) {
        pa1[i] = *(const bf16x8*)&K1s[wm * 32 + i * 16 + fr][ks * 32 + hi * 8];
        pa2[i] = *(const bf16x8*)&K2s[wm * 32 + i * 16 + fr][ks * 32 + hi * 8];
      }
#pragma unroll
      for (int j = 0; j < 2; ++j) {
        int row = wn * 32 + j * 16 + fr;
        int kbb = (ks * 4 + hi) ^ ((row >> 3) & 7);
        vb[j] = *(const bf16x8*)&Vts[row][kbb << 3];
      }
#pragma unroll
      for (int i = 0; i < 2; ++i)
#pragma unroll
        for (int j = 0; j < 2; ++j) {
          U1[i][j] = __builtin_amdgcn_mfma_f32_16x16x32_bf16(pa1[i], vb[j], U1[i][j], 0, 0, 0);
          U2[i][j] = __builtin_amdgcn_mfma_f32_16x16x32_bf16(pa2[i], vb[j], U2[i][j], 0, 0, 0);
        }
    }
    __builtin_amdgcn_s_setprio(0);
  }

  // ---- denominator: intra-wave reduce over fr, then cross-wave over wn ----
#pragma unroll
  for (int i = 0; i < 2; ++i)
#pragma unroll
    for (int r = 0; r < 4; ++r) {
#pragma unroll
      for (int m = 1; m < 16; m <<= 1) {
        lacc1[i][r] += __shfl_xor(lacc1[i][r], m);
        lacc2[i][r] += __shfl_xor(lacc2[i][r], m);
      }
    }
  if (fr == 0) {
#pragma unroll
    for (int i = 0; i < 2; ++i)
#pragma unroll
      for (int r = 0; r < 4; ++r) {
        int rl = i * 16 + hi * 4 + r;
        lred1[wn][wm][rl] = lacc1[i][r];
        lred2[wn][wm][rl] = lacc2[i][r];
      }
  }
  __syncthreads();
  float lam = lamp[0];

  // ---- epilogue: ctx = U1/l1 - lam*U2/l2 ----
#pragma unroll
  for (int i = 0; i < 2; ++i) {
#pragma unroll
    for (int r = 0; r < 4; ++r) {
      int rl = i * 16 + hi * 4 + r;
      float l1 = lred1[0][wm][rl] + lred1[1][wm][rl];
      float l2 = lred2[0][wm][rl] + lred2[1][wm][rl];
      float inv1 = 1.f / l1;
      float inv2 = lam / l2;
      int qg = q0 + wm * 32 + i * 16 + hi * 4 + r;
#pragma unroll
      for (int j = 0; j < 2; ++j) {
        int dh = wn * 32 + j * 16 + fr;
        ctx[((size_t)bh * 1024 + qg) * 64 + dh] = U1[i][j][r] * inv1 - U2[i][j][r] * inv2;
      }
    }
  }
}

// ---------------- group norm (unchanged) ----------------
__global__ __launch_bounds__(256) void gn_stats(
    const float* __restrict__ ctx, float2* __restrict__ mv)
{
  int bh = blockIdx.x;
  const float4* p = (const float4*)(ctx + (size_t)bh * 65536);
  float s = 0.f, ss = 0.f;
  for (int i = threadIdx.x; i < 16384; i += 256) {
    float4 v = p[i];
    s  += v.x + v.y + v.z + v.w;
    ss += v.x*v.x + v.y*v.y + v.z*v.z + v.w*v.w;
  }
#pragma unroll
  for (int o = 32; o > 0; o >>= 1) { s += __shfl_down(s, o); ss += __shfl_down(ss, o); }
  __shared__ float ws0[4], ws1[4];
  int w = threadIdx.x >> 6, ln = threadIdx.x & 63;
  if (ln == 0) { ws0[w] = s; ws1[w] = ss; }
  __syncthreads();
  if (threadIdx.x == 0) {
    float S = ws0[0] + ws0[1] + ws0[2] + ws0[3];
    float SS = ws1[0] + ws1[1] + ws1[2] + ws1[3];
    float mean = S / 65536.f;
    float var = SS / 65536.f - mean * mean;
    mv[bh] = make_float2(mean, rsqrtf(var + 1e-5f));
  }
}

__global__ __launch_bounds__(256) void gn_apply(
    const float* __restrict__ ctx, const float2* __restrict__ mv,
    const float* __restrict__ gw, const float* __restrict__ gb,
    u16* __restrict__ normed)
{
  unsigned idx = blockIdx.x * 256u + threadIdx.x;
  unsigned i = idx * 4;
  unsigned d = i & 1023u;
  unsigned srow = i >> 10;
  unsigned b = srow >> 10;
  unsigned h = d >> 6, dh = d & 63u;
  float2 m = mv[b * 16 + h];
  float4 x = *(const float4*)&ctx[(((size_t)(b * 16 + h)) * 1024 + (srow & 1023u)) * 64 + dh];
  float4 g = *(const float4*)&gw[d];
  float4 be = *(const float4*)&gb[d];
  union { u16 hh[4]; uint2 u2; } p;
  p.hh[0] = f2b(((x.x - m.x) * m.y * g.x + be.x) * 0.8f);
  p.hh[1] = f2b(((x.y - m.x) * m.y * g.y + be.y) * 0.8f);
  p.hh[2] = f2b(((x.z - m.x) * m.y * g.z + be.z) * 0.8f);
  p.hh[3] = f2b(((x.w - m.x) * m.y * g.w + be.w) * 0.8f);
  *(uint2*)(normed + i) = p.u2;
}

// ---------------- launch ----------------
extern "C" void kernel_launch(void* const* d_in, const int* in_sizes, int n_in,
                              void* d_out, int out_size, void* d_ws, size_t ws_size,
                              hipStream_t stream) {
  (void)in_sizes; (void)n_in; (void)out_size; (void)ws_size;
  const float* x   = (const float*)d_in[0];
  const float* aff = (const float*)d_in[1];
  const float* Wq  = (const float*)d_in[2];
  const float* bq  = (const float*)d_in[3];
  const float* Wk  = (const float*)d_in[4];
  const float* bk  = (const float*)d_in[5];
  const float* Wv  = (const float*)d_in[6];
  const float* bv  = (const float*)d_in[7];
  const float* Wo  = (const float*)d_in[8];
  const float* bo  = (const float*)d_in[9];
  const float* gw  = (const float*)d_in[10];
  const float* gb  = (const float*)d_in[11];
  const float* lam = (const float*)d_in[12];
  float* out = (float*)d_out;

  char* w = (char*)d_ws;
  u16*    xb    = (u16*)(w);
  u16*    Wcat  = (u16*)(w + 8388608);
  u16*    Wob   = (u16*)(w + 18874368);
  float*  bcat  = (float*)(w + 20971520);
  u16*    q1t   = (u16*)(w + 20992000);
  u16*    q2t   = (u16*)(w + 29380608);
  u16*    k1t   = (u16*)(w + 37769216);
  u16*    k2t   = (u16*)(w + 46157824);
  u16*    vtT   = (u16*)(w + 54546432);   // [bh][dh][s] transposed
  float*  logL  = (float*)(w + 62935040);
  float*  ctab  = (float*)(w + 62951424);
  float*  stab  = (float*)(w + 63082496);
  float*  ctx   = (float*)(w + 63475712);
  float2* mv    = (float2*)(w + 80252928);
  u16*    normed= (u16*)(w + 80253440);

  convert_kernel<<<10245, 256, 0, stream>>>(x, Wq, Wk, Wv, Wo, bq, bk, bv, xb, Wcat, Wob, bcat);
  rope_table<<<128, 256, 0, stream>>>(ctab, stab);
  gemm_nt<0><<<dim3(40, 32), 256, 0, stream>>>(xb, Wcat, bcat, nullptr, q1t, q2t, k1t, k2t, vtT, ctab, stab, 5120);
  scan_logl<<<4, 1024, 0, stream>>>(aff, logL);
  attn_fused<<<1024, 256, 0, stream>>>(q1t, q2t, k1t, k2t, vtT, logL, lam, ctx);
  gn_stats<<<64, 256, 0, stream>>>(ctx, mv);
  gn_apply<<<4096, 256, 0, stream>>>(ctx, mv, gw, gb, normed);
  gemm_nt<1><<<dim3(8, 32), 256, 0, stream>>>(normed, Wob, bo, out, nullptr, nullptr, nullptr, nullptr, nullptr, ctab, stab, 1024);
}

// Round 11
// 217.198 us; speedup vs baseline: 1.6650x; 1.6650x over previous
//
#include <hip/hip_runtime.h>
#include <math.h>

typedef float  f32x4  __attribute__((ext_vector_type(4)));
typedef short  bf16x8 __attribute__((ext_vector_type(8)));
typedef unsigned short u16;

__device__ __forceinline__ u16 f2b(float f) {
  union { float f; unsigned u; } v; v.f = f;
  unsigned r = v.u + 0x7FFFu + ((v.u >> 16) & 1u);
  return (u16)(r >> 16);
}
__device__ __forceinline__ float b2f(u16 h) {
  union { unsigned u; float f; } v; v.u = ((unsigned)h) << 16;
  return v.f;
}

// async global->LDS, 16B per lane; dest = wave-uniform base + lane*16
__device__ __forceinline__ void gl_lds16(const u16* g, u16* l) {
  __builtin_amdgcn_global_load_lds(
      (const __attribute__((address_space(1))) unsigned*)g,
      (__attribute__((address_space(3))) unsigned*)l, 16, 0, 0);
}

// ---------------- fp32 -> bf16 conversion / packing ----------------
__global__ __launch_bounds__(256) void convert_kernel(
    const float* __restrict__ x,  const float* __restrict__ Wq,
    const float* __restrict__ Wk, const float* __restrict__ Wv,
    const float* __restrict__ Wo, const float* __restrict__ bq,
    const float* __restrict__ bk, const float* __restrict__ bv,
    u16* __restrict__ xb, u16* __restrict__ Wcat, u16* __restrict__ Wob,
    float* __restrict__ bcat)
{
  long i = ((long)blockIdx.x * 256 + threadIdx.x) * 4;
  if (i < 10485760L) {
    const float* src; u16* dst; long o;
    if (i < 4194304L)      { src = x;  dst = xb;             o = i; }
    else if (i < 6291456L) { src = Wq; dst = Wcat;           o = i - 4194304L; }
    else if (i < 8388608L) { src = Wk; dst = Wcat + 2097152; o = i - 6291456L; }
    else if (i < 9437184L) { src = Wv; dst = Wcat + 4194304; o = i - 8388608L; }
    else                   { src = Wo; dst = Wob;            o = i - 9437184L; }
    float4 v = *(const float4*)(src + o);
    union { u16 h[4]; uint2 u2; } p;
    p.h[0] = f2b(v.x); p.h[1] = f2b(v.y); p.h[2] = f2b(v.z); p.h[3] = f2b(v.w);
    *(uint2*)(dst + o) = p.u2;
  } else if (i < 10490880L) {
    long j = i - 10485760L;
    const float* src; long o;
    if (j < 2048)      { src = bq; o = j; }
    else if (j < 4096) { src = bk; o = j - 2048; }
    else               { src = bv; o = j - 4096; }
    *(float4*)(bcat + j) = *(const float4*)(src + o);
  }
}

// ---------------- RoPE cos/sin table: [s][i], i=0..31 ----------------
__global__ __launch_bounds__(256) void rope_table(
    float* __restrict__ ctab, float* __restrict__ stab)
{
  int idx = blockIdx.x * 256 + threadIdx.x;   // 0..32767
  int s = idx >> 5, i = idx & 31;
  float freq = expf(-(float)i * (9.210340371976184f / 32.f));  // 10000^(-i/32)
  float ang = (float)s * freq;
  ctab[idx] = cosf(ang);
  stab[idx] = sinf(ang);
}

// ---------------- MFMA NT GEMM, m97 structure (unchanged) ----------------
template<int EPI>
__global__ __launch_bounds__(256) void gemm_nt(
    const u16* __restrict__ A, const u16* __restrict__ Bw,
    const float* __restrict__ bias, float* __restrict__ outF,
    u16* __restrict__ q1t, u16* __restrict__ q2t,
    u16* __restrict__ k1t, u16* __restrict__ k2t, u16* __restrict__ vtT,
    const float* __restrict__ ctab, const float* __restrict__ stab,
    int N)
{
  const int K = 1024;
  __shared__ u16 As[128 * 32];
  __shared__ u16 Bs[128 * 32];
  int tid  = threadIdx.x;
  int lane = tid & 63, wave = tid >> 6;
  int wm = wave >> 1, wn = wave & 1;
  int m0 = blockIdx.y * 128, n0 = blockIdx.x * 128;
  int fr = lane & 15, hi = lane >> 4;

  int c0 = wave * 128 + lane;
  int c1 = c0 + 64;
  int r0 = c0 >> 2, q0_ = c0 & 3;
  int r1 = c1 >> 2, q1_ = c1 & 3;
  u16* asb0 = &As[wave * 1024];
  u16* asb1 = &As[wave * 1024 + 512];
  u16* bsb0 = &Bs[wave * 1024];
  u16* bsb1 = &Bs[wave * 1024 + 512];
  const u16* ag0 = A  + (size_t)(m0 + r0) * K + q0_ * 8;
  const u16* ag1 = A  + (size_t)(m0 + r1) * K + q1_ * 8;
  const u16* bg0 = Bw + (size_t)(n0 + r0) * K + q0_ * 8;
  const u16* bg1 = Bw + (size_t)(n0 + r1) * K + q1_ * 8;

  f32x4 acc[4][4];
#pragma unroll
  for (int i = 0; i < 4; ++i)
#pragma unroll
    for (int j = 0; j < 4; ++j) acc[i][j] = 0.0f;

  for (int kk0 = 0; kk0 < K; kk0 += 32) {
    __syncthreads();
    gl_lds16(ag0 + kk0, asb0);
    gl_lds16(ag1 + kk0, asb1);
    gl_lds16(bg0 + kk0, bsb0);
    gl_lds16(bg1 + kk0, bsb1);
    __syncthreads();
    bf16x8 af[4], bfv[4];
#pragma unroll
    for (int f = 0; f < 4; ++f) {
      af[f]  = *(const bf16x8*)&As[(wm * 64 + f * 16 + fr) * 32 + hi * 8];
      bfv[f] = *(const bf16x8*)&Bs[(wn * 64 + f * 16 + fr) * 32 + hi * 8];
    }
#pragma unroll
    for (int i = 0; i < 4; ++i)
#pragma unroll
      for (int j = 0; j < 4; ++j)
        acc[i][j] = __builtin_amdgcn_mfma_f32_16x16x32_bf16(af[i], bfv[j], acc[i][j], 0, 0, 0);
  }

  int rg = lane >> 4;
  if (EPI == 0) {
    if (n0 < 4096) {
      u16* dst; int base;
      if (n0 < 1024)      { dst = q1t; base = 0; }
      else if (n0 < 2048) { dst = q2t; base = 1024; }
      else if (n0 < 3072) { dst = k1t; base = 2048; }
      else                { dst = k2t; base = 3072; }
      float qs = (n0 < 2048) ? 0.18033688011112042f : 1.0f;   // 0.125*log2e
#pragma unroll
      for (int i = 0; i < 4; ++i) {
#pragma unroll
        for (int e = 0; e < 4; ++e) {
          int m = m0 + wm * 64 + i * 16 + rg * 4 + e;
          int b = m >> 10, s = m & 1023;
#pragma unroll
          for (int j = 0; j < 2; ++j) {
            int n_lo = n0 + wn * 64 + j * 16 + fr;
            int feat = n_lo - base;
            int h = feat >> 6, dh = feat & 63;   // dh < 32
            float a1 = acc[i][j][e]     + bias[n_lo];
            float a2 = acc[i][j + 2][e] + bias[n_lo + 32];
            float cs = ctab[s * 32 + dh], sn = stab[s * 32 + dh];
            size_t rowb = ((size_t)(b * 16 + h) * 1024 + s) * 64;
            dst[rowb + dh]      = f2b((a1 * cs - a2 * sn) * qs);
            dst[rowb + dh + 32] = f2b((a1 * sn + a2 * cs) * qs);
          }
        }
      }
    } else {
      // v tensor: TRANSPOSED store [bh][dh][s]
#pragma unroll
      for (int i = 0; i < 4; ++i) {
        int mbase = m0 + wm * 64 + i * 16 + rg * 4;
        int b = mbase >> 10, s0 = mbase & 1023;
#pragma unroll
        for (int j = 0; j < 4; ++j) {
          int n = n0 + wn * 64 + j * 16 + fr;
          int feat = n - 4096;
          int h = feat >> 6, dh = feat & 63;
          float bv = bias[n];
          union { u16 hh[4]; uint2 u2; } p;
#pragma unroll
          for (int e = 0; e < 4; ++e) p.hh[e] = f2b(acc[i][j][e] + bv);
          *(uint2*)&vtT[((size_t)(b * 16 + h) * 64 + dh) * 1024 + s0] = p.u2;
        }
      }
    }
  } else {
#pragma unroll
    for (int i = 0; i < 4; ++i)
#pragma unroll
      for (int j = 0; j < 4; ++j)
#pragma unroll
        for (int e = 0; e < 4; ++e) {
          int m = m0 + wm * 64 + i * 16 + rg * 4 + e;
          int n = n0 + wn * 64 + j * 16 + fr;
          outF[(size_t)m * N + n] = acc[i][j][e] + bias[n];
        }
  }
}

// ---------------- logL scan (base-2) ----------------
__global__ __launch_bounds__(1024) void scan_logl(
    const float* __restrict__ a, float* __restrict__ logL)
{
  __shared__ float sh[1024];
  int b = blockIdx.x, t = threadIdx.x;
  float v = (t == 0) ? 0.f : log2f(a[b * 1023 + t - 1]);
  sh[t] = v;
  __syncthreads();
  for (int off = 1; off < 1024; off <<= 1) {
    float add = (t >= off) ? sh[t - off] : 0.f;
    __syncthreads();
    sh[t] += add;
    __syncthreads();
  }
  logL[b * 1024 + t] = sh[t];
}

// ---------------- fused MFMA attention v6 ----------------
// = round-8 kernel VERBATIM (best measured 88us, VGPR 100) with ONE change:
// XCD-grouped 1-D block swizzle (bh=(id&7)*8+(id>>7)) so each XCD's 8 bh
// (3.2MB K/V) L2-fit -> stage loads become L2 hits (r9: FETCH 106->21MB).
// NO launch_bounds min-waves (r10 lesson: forced 64 VGPR -> scratch spill).
__global__ __launch_bounds__(256) void attn_fused(
    const u16* __restrict__ q1t, const u16* __restrict__ q2t,
    const u16* __restrict__ k1t, const u16* __restrict__ k2t,
    const u16* __restrict__ vtT,
    const float* __restrict__ logL, const float* __restrict__ lamp,
    float* __restrict__ ctx)
{
  __shared__ u16 K1s[64][72];   // K1 during QK^T, P1 during PV
  __shared__ u16 K2s[64][72];   // K2 during QK^T, P2 during PV
  __shared__ u16 Vts[64][72];   // V^T [dh][k], k-blocks XOR-swizzled by (dh>>3)&7
  __shared__ float lred1[2][2][32];
  __shared__ float lred2[2][2][32];

  int tid  = threadIdx.x;
  int lane = tid & 63, wave = tid >> 6;
  int wm = wave >> 1, wn = wave & 1;
  int id = blockIdx.x;
  int bh = (id & 7) * 8 + (id >> 7);        // XCD-grouped: 8 bh per XCD (L2-fit)
  int q0 = ((id >> 3) & 15) * 64;
  int b = bh >> 4;
  int fr = lane & 15, hi = lane >> 4;

  bf16x8 qf1[2][2], qf2[2][2];
#pragma unroll
  for (int i = 0; i < 2; ++i)
#pragma unroll
    for (int ks = 0; ks < 2; ++ks) {
      size_t off = ((size_t)bh * 1024 + q0 + wm * 32 + i * 16 + fr) * 64 + ks * 32 + hi * 8;
      qf1[i][ks] = *(const bf16x8*)(q1t + off);
      qf2[i][ks] = *(const bf16x8*)(q2t + off);
    }
  float Lq[2][4];
#pragma unroll
  for (int i = 0; i < 2; ++i)
#pragma unroll
    for (int r = 0; r < 4; ++r)
      Lq[i][r] = logL[b * 1024 + q0 + wm * 32 + i * 16 + hi * 4 + r];

  float lacc1[2][4], lacc2[2][4];
  f32x4 U1[2][2], U2[2][2];
#pragma unroll
  for (int i = 0; i < 2; ++i)
#pragma unroll
    for (int r = 0; r < 4; ++r) { lacc1[i][r] = 0.f; lacc2[i][r] = 0.f; }
#pragma unroll
  for (int i = 0; i < 2; ++i)
#pragma unroll
    for (int j = 0; j < 2; ++j) { U1[i][j] = 0.f; U2[i][j] = 0.f; }

  int sr = tid >> 2, sc0 = (tid & 3) * 16;
  int swz = (sr >> 3) & 7;
  int blk0 = ((sc0 >> 3) ^ swz) << 3;
  int blk1 = (((sc0 >> 3) + 1) ^ swz) << 3;

  // LDS byte addresses for packed P writes (row wm*32+hi*4, col wn*32+fr)
  unsigned a1base = (unsigned)(size_t)&K1s[wm * 32 + hi * 4][wn * 32 + fr];
  unsigned a2base = (unsigned)(size_t)&K2s[wm * 32 + hi * 4][wn * 32 + fr];

  for (int kt = 0; kt < 16; ++kt) {
    __syncthreads();   // (1) prev PV reads done
    size_t gb = ((size_t)bh * 1024 + kt * 64 + sr) * 64 + sc0;
    size_t gv = (size_t)bh * 65536 + (size_t)sr * 1024 + kt * 64 + sc0;
    bf16x8 a0 = *(const bf16x8*)(k1t + gb), a1 = *(const bf16x8*)(k1t + gb + 8);
    bf16x8 b0 = *(const bf16x8*)(k2t + gb), b1 = *(const bf16x8*)(k2t + gb + 8);
    bf16x8 v0 = *(const bf16x8*)(vtT + gv), v1 = *(const bf16x8*)(vtT + gv + 8);
    *(bf16x8*)&K1s[sr][sc0]     = a0;  *(bf16x8*)&K1s[sr][sc0 + 8] = a1;
    *(bf16x8*)&K2s[sr][sc0]     = b0;  *(bf16x8*)&K2s[sr][sc0 + 8] = b1;
    *(bf16x8*)&Vts[sr][blk0]    = v0;  *(bf16x8*)&Vts[sr][blk1]    = v1;
    float Ltl[2];
#pragma unroll
    for (int j = 0; j < 2; ++j) Ltl[j] = logL[b * 1024 + kt * 64 + wn * 32 + j * 16 + fr];
    __syncthreads();   // (2) stage complete

    // ---- QK^T ----
    f32x4 S1[2][2], S2[2][2];
#pragma unroll
    for (int i = 0; i < 2; ++i)
#pragma unroll
      for (int j = 0; j < 2; ++j) { S1[i][j] = 0.f; S2[i][j] = 0.f; }
    __builtin_amdgcn_s_setprio(1);
#pragma unroll
    for (int ks = 0; ks < 2; ++ks) {
      bf16x8 kf1[2], kf2[2];
#pragma unroll
      for (int j = 0; j < 2; ++j) {
        kf1[j] = *(const bf16x8*)&K1s[wn * 32 + j * 16 + fr][ks * 32 + hi * 8];
        kf2[j] = *(const bf16x8*)&K2s[wn * 32 + j * 16 + fr][ks * 32 + hi * 8];
      }
#pragma unroll
      for (int i = 0; i < 2; ++i)
#pragma unroll
        for (int j = 0; j < 2; ++j) {
          S1[i][j] = __builtin_amdgcn_mfma_f32_16x16x32_bf16(qf1[i][ks], kf1[j], S1[i][j], 0, 0, 0);
          S2[i][j] = __builtin_amdgcn_mfma_f32_16x16x32_bf16(qf2[i][ks], kf2[j], S2[i][j], 0, 0, 0);
        }
    }
    __builtin_amdgcn_s_setprio(0);
    __syncthreads();   // (3) all K reads done -> K-space reusable as P

    // ---- exponentials (log2 domain) + packed P write ----
#pragma unroll
    for (int i = 0; i < 2; ++i) {
#pragma unroll
      for (int r = 0; r < 4; ++r) {
        float lq = Lq[i][r];
        float e1j[2], e2j[2], p1j[2], p2j[2];
#pragma unroll
        for (int j = 0; j < 2; ++j) {
          float nd = -fabsf(Ltl[j] - lq);
          float t1, t2, ec;
          asm("v_exp_f32 %0, %1" : "=v"(t1) : "v"(S1[i][j][r]));
          asm("v_exp_f32 %0, %1" : "=v"(t2) : "v"(S2[i][j][r]));
          asm("v_exp_f32 %0, %1" : "=v"(ec) : "v"(nd));
          e1j[j] = t1; e2j[j] = t2;
          p1j[j] = t1 * ec; p2j[j] = t2 * ec;
        }
        lacc1[i][r] += e1j[0] + e1j[1];
        lacc2[i][r] += e2j[0] + e2j[1];
        unsigned off = (unsigned)((i * 16 + r) * 144);
        unsigned ad1 = a1base + off, ad2 = a2base + off;
        unsigned pk1, pk2;
        asm("v_cvt_pk_bf16_f32 %0, %1, %2" : "=v"(pk1) : "v"(p1j[0]), "v"(p1j[1]));
        asm("v_cvt_pk_bf16_f32 %0, %1, %2" : "=v"(pk2) : "v"(p2j[0]), "v"(p2j[1]));
        asm volatile("ds_write_b16 %0, %1\n\tds_write_b16_d16_hi %0, %1 offset:32"
                     :: "v"(ad1), "v"(pk1) : "memory");
        asm volatile("ds_write_b16 %0, %1\n\tds_write_b16_d16_hi %0, %1 offset:32"
                     :: "v"(ad2), "v"(pk2) : "memory");
      }
    }
    __syncthreads();   // (4) P complete

    // ---- PV: U += P * V (P in K1s/K2s, V^T in Vts) ----
    __builtin_amdgcn_s_setprio(1);
#pragma unroll
    for (int ks = 0; ks < 2; ++ks) {
      bf16x8 pa1[2], pa2[2], vb[2];
#pragma unroll
      for (int i = 0; i < 2; ++i) {
        pa1[i] = *(const bf16x8*)&K1s[wm * 32 + i * 16 + fr][ks * 32 + hi * 8];
        pa2[i] = *(const bf16x8*)&K2s[wm * 32 + i * 16 + fr][ks * 32 + hi * 8];
      }
#pragma unroll
      for (int j = 0; j < 2; ++j) {
        int row = wn * 32 + j * 16 + fr;
        int kbb = (ks * 4 + hi) ^ ((row >> 3) & 7);
        vb[j] = *(const bf16x8*)&Vts[row][kbb << 3];
      }
#pragma unroll
      for (int i = 0; i < 2; ++i)
#pragma unroll
        for (int j = 0; j < 2; ++j) {
          U1[i][j] = __builtin_amdgcn_mfma_f32_16x16x32_bf16(pa1[i], vb[j], U1[i][j], 0, 0, 0);
          U2[i][j] = __builtin_amdgcn_mfma_f32_16x16x32_bf16(pa2[i], vb[j], U2[i][j], 0, 0, 0);
        }
    }
    __builtin_amdgcn_s_setprio(0);
  }

  // ---- denominator: intra-wave reduce over fr, then cross-wave over wn ----
#pragma unroll
  for (int i = 0; i < 2; ++i)
#pragma unroll
    for (int r = 0; r < 4; ++r) {
#pragma unroll
      for (int m = 1; m < 16; m <<= 1) {
        lacc1[i][r] += __shfl_xor(lacc1[i][r], m);
        lacc2[i][r] += __shfl_xor(lacc2[i][r], m);
      }
    }
  if (fr == 0) {
#pragma unroll
    for (int i = 0; i < 2; ++i)
#pragma unroll
      for (int r = 0; r < 4; ++r) {
        int rl = i * 16 + hi * 4 + r;
        lred1[wn][wm][rl] = lacc1[i][r];
        lred2[wn][wm][rl] = lacc2[i][r];
      }
  }
  __syncthreads();
  float lam = lamp[0];

  // ---- epilogue: ctx = U1/l1 - lam*U2/l2 ----
#pragma unroll
  for (int i = 0; i < 2; ++i) {
#pragma unroll
    for (int r = 0; r < 4; ++r) {
      int rl = i * 16 + hi * 4 + r;
      float l1 = lred1[0][wm][rl] + lred1[1][wm][rl];
      float l2 = lred2[0][wm][rl] + lred2[1][wm][rl];
      float inv1 = 1.f / l1;
      float inv2 = lam / l2;
      int qg = q0 + wm * 32 + i * 16 + hi * 4 + r;
#pragma unroll
      for (int j = 0; j < 2; ++j) {
        int dh = wn * 32 + j * 16 + fr;
        ctx[((size_t)bh * 1024 + qg) * 64 + dh] = U1[i][j][r] * inv1 - U2[i][j][r] * inv2;
      }
    }
  }
}

// ---------------- group norm (unchanged) ----------------
__global__ __launch_bounds__(256) void gn_stats(
    const float* __restrict__ ctx, float2* __restrict__ mv)
{
  int bh = blockIdx.x;
  const float4* p = (const float4*)(ctx + (size_t)bh * 65536);
  float s = 0.f, ss = 0.f;
  for (int i = threadIdx.x; i < 16384; i += 256) {
    float4 v = p[i];
    s  += v.x + v.y + v.z + v.w;
    ss += v.x*v.x + v.y*v.y + v.z*v.z + v.w*v.w;
  }
#pragma unroll
  for (int o = 32; o > 0; o >>= 1) { s += __shfl_down(s, o); ss += __shfl_down(ss, o); }
  __shared__ float ws0[4], ws1[4];
  int w = threadIdx.x >> 6, ln = threadIdx.x & 63;
  if (ln == 0) { ws0[w] = s; ws1[w] = ss; }
  __syncthreads();
  if (threadIdx.x == 0) {
    float S = ws0[0] + ws0[1] + ws0[2] + ws0[3];
    float SS = ws1[0] + ws1[1] + ws1[2] + ws1[3];
    float mean = S / 65536.f;
    float var = SS / 65536.f - mean * mean;
    mv[bh] = make_float2(mean, rsqrtf(var + 1e-5f));
  }
}

__global__ __launch_bounds__(256) void gn_apply(
    const float* __restrict__ ctx, const float2* __restrict__ mv,
    const float* __restrict__ gw, const float* __restrict__ gb,
    u16* __restrict__ normed)
{
  unsigned idx = blockIdx.x * 256u + threadIdx.x;
  unsigned i = idx * 4;
  unsigned d = i & 1023u;
  unsigned srow = i >> 10;
  unsigned b = srow >> 10;
  unsigned h = d >> 6, dh = d & 63u;
  float2 m = mv[b * 16 + h];
  float4 x = *(const float4*)&ctx[(((size_t)(b * 16 + h)) * 1024 + (srow & 1023u)) * 64 + dh];
  float4 g = *(const float4*)&gw[d];
  float4 be = *(const float4*)&gb[d];
  union { u16 hh[4]; uint2 u2; } p;
  p.hh[0] = f2b(((x.x - m.x) * m.y * g.x + be.x) * 0.8f);
  p.hh[1] = f2b(((x.y - m.x) * m.y * g.y + be.y) * 0.8f);
  p.hh[2] = f2b(((x.z - m.x) * m.y * g.z + be.z) * 0.8f);
  p.hh[3] = f2b(((x.w - m.x) * m.y * g.w + be.w) * 0.8f);
  *(uint2*)(normed + i) = p.u2;
}

// ---------------- launch ----------------
extern "C" void kernel_launch(void* const* d_in, const int* in_sizes, int n_in,
                              void* d_out, int out_size, void* d_ws, size_t ws_size,
                              hipStream_t stream) {
  (void)in_sizes; (void)n_in; (void)out_size; (void)ws_size;
  const float* x   = (const float*)d_in[0];
  const float* aff = (const float*)d_in[1];
  const float* Wq  = (const float*)d_in[2];
  const float* bq  = (const float*)d_in[3];
  const float* Wk  = (const float*)d_in[4];
  const float* bk  = (const float*)d_in[5];
  const float* Wv  = (const float*)d_in[6];
  const float* bv  = (const float*)d_in[7];
  const float* Wo  = (const float*)d_in[8];
  const float* bo  = (const float*)d_in[9];
  const float* gw  = (const float*)d_in[10];
  const float* gb  = (const float*)d_in[11];
  const float* lam = (const float*)d_in[12];
  float* out = (float*)d_out;

  char* w = (char*)d_ws;
  u16*    xb    = (u16*)(w);
  u16*    Wcat  = (u16*)(w + 8388608);
  u16*    Wob   = (u16*)(w + 18874368);
  float*  bcat  = (float*)(w + 20971520);
  u16*    q1t   = (u16*)(w + 20992000);
  u16*    q2t   = (u16*)(w + 29380608);
  u16*    k1t   = (u16*)(w + 37769216);
  u16*    k2t   = (u16*)(w + 46157824);
  u16*    vtT   = (u16*)(w + 54546432);   // [bh][dh][s] transposed
  float*  logL  = (float*)(w + 62935040);
  float*  ctab  = (float*)(w + 62951424);
  float*  stab  = (float*)(w + 63082496);
  float*  ctx   = (float*)(w + 63475712);
  float2* mv    = (float2*)(w + 80252928);
  u16*    normed= (u16*)(w + 80253440);

  convert_kernel<<<10245, 256, 0, stream>>>(x, Wq, Wk, Wv, Wo, bq, bk, bv, xb, Wcat, Wob, bcat);
  rope_table<<<128, 256, 0, stream>>>(ctab, stab);
  gemm_nt<0><<<dim3(40, 32), 256, 0, stream>>>(xb, Wcat, bcat, nullptr, q1t, q2t, k1t, k2t, vtT, ctab, stab, 5120);
  scan_logl<<<4, 1024, 0, stream>>>(aff, logL);
  attn_fused<<<1024, 256, 0, stream>>>(q1t, q2t, k1t, k2t, vtT, logL, lam, ctx);
  gn_stats<<<64, 256, 0, stream>>>(ctx, mv);
  gn_apply<<<4096, 256, 0, stream>>>(ctx, mv, gw, gb, normed);
  gemm_nt<1><<<dim3(8, 32), 256, 0, stream>>>(normed, Wob, bo, out, nullptr, nullptr, nullptr, nullptr, nullptr, ctab, stab, 1024);
}

// Round 12
// 215.926 us; speedup vs baseline: 1.6748x; 1.0059x over previous
//
#include <hip/hip_runtime.h>
#include <math.h>

typedef float  f32x4  __attribute__((ext_vector_type(4)));
typedef short  bf16x8 __attribute__((ext_vector_type(8)));
typedef unsigned short u16;

__device__ __forceinline__ u16 f2b(float f) {
  union { float f; unsigned u; } v; v.f = f;
  unsigned r = v.u + 0x7FFFu + ((v.u >> 16) & 1u);
  return (u16)(r >> 16);
}
__device__ __forceinline__ float b2f(u16 h) {
  union { unsigned u; float f; } v; v.u = ((unsigned)h) << 16;
  return v.f;
}

// async global->LDS, 16B per lane; dest = wave-uniform base + lane*16
__device__ __forceinline__ void gl_lds16(const u16* g, u16* l) {
  __builtin_amdgcn_global_load_lds(
      (const __attribute__((address_space(1))) unsigned*)g,
      (__attribute__((address_space(3))) unsigned*)l, 16, 0, 0);
}

// ---------------- fp32 -> bf16 conversion / packing ----------------
__global__ __launch_bounds__(256) void convert_kernel(
    const float* __restrict__ x,  const float* __restrict__ Wq,
    const float* __restrict__ Wk, const float* __restrict__ Wv,
    const float* __restrict__ Wo, const float* __restrict__ bq,
    const float* __restrict__ bk, const float* __restrict__ bv,
    u16* __restrict__ xb, u16* __restrict__ Wcat, u16* __restrict__ Wob,
    float* __restrict__ bcat)
{
  long i = ((long)blockIdx.x * 256 + threadIdx.x) * 4;
  if (i < 10485760L) {
    const float* src; u16* dst; long o;
    if (i < 4194304L)      { src = x;  dst = xb;             o = i; }
    else if (i < 6291456L) { src = Wq; dst = Wcat;           o = i - 4194304L; }
    else if (i < 8388608L) { src = Wk; dst = Wcat + 2097152; o = i - 6291456L; }
    else if (i < 9437184L) { src = Wv; dst = Wcat + 4194304; o = i - 8388608L; }
    else                   { src = Wo; dst = Wob;            o = i - 9437184L; }
    float4 v = *(const float4*)(src + o);
    union { u16 h[4]; uint2 u2; } p;
    p.h[0] = f2b(v.x); p.h[1] = f2b(v.y); p.h[2] = f2b(v.z); p.h[3] = f2b(v.w);
    *(uint2*)(dst + o) = p.u2;
  } else if (i < 10490880L) {
    long j = i - 10485760L;
    const float* src; long o;
    if (j < 2048)      { src = bq; o = j; }
    else if (j < 4096) { src = bk; o = j - 2048; }
    else               { src = bv; o = j - 4096; }
    *(float4*)(bcat + j) = *(const float4*)(src + o);
  }
}

// ---------------- RoPE cos/sin table: [s][i], i=0..31 ----------------
__global__ __launch_bounds__(256) void rope_table(
    float* __restrict__ ctab, float* __restrict__ stab)
{
  int idx = blockIdx.x * 256 + threadIdx.x;   // 0..32767
  int s = idx >> 5, i = idx & 31;
  float freq = expf(-(float)i * (9.210340371976184f / 32.f));  // 10000^(-i/32)
  float ang = (float)s * freq;
  ctab[idx] = cosf(ang);
  stab[idx] = sinf(ang);
}

// ---------------- MFMA NT GEMM, m97 structure (unchanged) ----------------
template<int EPI>
__global__ __launch_bounds__(256) void gemm_nt(
    const u16* __restrict__ A, const u16* __restrict__ Bw,
    const float* __restrict__ bias, float* __restrict__ outF,
    u16* __restrict__ q1t, u16* __restrict__ q2t,
    u16* __restrict__ k1t, u16* __restrict__ k2t, u16* __restrict__ vtT,
    const float* __restrict__ ctab, const float* __restrict__ stab,
    int N)
{
  const int K = 1024;
  __shared__ u16 As[128 * 32];
  __shared__ u16 Bs[128 * 32];
  int tid  = threadIdx.x;
  int lane = tid & 63, wave = tid >> 6;
  int wm = wave >> 1, wn = wave & 1;
  int m0 = blockIdx.y * 128, n0 = blockIdx.x * 128;
  int fr = lane & 15, hi = lane >> 4;

  int c0 = wave * 128 + lane;
  int c1 = c0 + 64;
  int r0 = c0 >> 2, q0_ = c0 & 3;
  int r1 = c1 >> 2, q1_ = c1 & 3;
  u16* asb0 = &As[wave * 1024];
  u16* asb1 = &As[wave * 1024 + 512];
  u16* bsb0 = &Bs[wave * 1024];
  u16* bsb1 = &Bs[wave * 1024 + 512];
  const u16* ag0 = A  + (size_t)(m0 + r0) * K + q0_ * 8;
  const u16* ag1 = A  + (size_t)(m0 + r1) * K + q1_ * 8;
  const u16* bg0 = Bw + (size_t)(n0 + r0) * K + q0_ * 8;
  const u16* bg1 = Bw + (size_t)(n0 + r1) * K + q1_ * 8;

  f32x4 acc[4][4];
#pragma unroll
  for (int i = 0; i < 4; ++i)
#pragma unroll
    for (int j = 0; j < 4; ++j) acc[i][j] = 0.0f;

  for (int kk0 = 0; kk0 < K; kk0 += 32) {
    __syncthreads();
    gl_lds16(ag0 + kk0, asb0);
    gl_lds16(ag1 + kk0, asb1);
    gl_lds16(bg0 + kk0, bsb0);
    gl_lds16(bg1 + kk0, bsb1);
    __syncthreads();
    bf16x8 af[4], bfv[4];
#pragma unroll
    for (int f = 0; f < 4; ++f) {
      af[f]  = *(const bf16x8*)&As[(wm * 64 + f * 16 + fr) * 32 + hi * 8];
      bfv[f] = *(const bf16x8*)&Bs[(wn * 64 + f * 16 + fr) * 32 + hi * 8];
    }
#pragma unroll
    for (int i = 0; i < 4; ++i)
#pragma unroll
      for (int j = 0; j < 4; ++j)
        acc[i][j] = __builtin_amdgcn_mfma_f32_16x16x32_bf16(af[i], bfv[j], acc[i][j], 0, 0, 0);
  }

  int rg = lane >> 4;
  if (EPI == 0) {
    if (n0 < 4096) {
      u16* dst; int base;
      if (n0 < 1024)      { dst = q1t; base = 0; }
      else if (n0 < 2048) { dst = q2t; base = 1024; }
      else if (n0 < 3072) { dst = k1t; base = 2048; }
      else                { dst = k2t; base = 3072; }
      float qs = (n0 < 2048) ? 0.18033688011112042f : 1.0f;   // 0.125*log2e
#pragma unroll
      for (int i = 0; i < 4; ++i) {
#pragma unroll
        for (int e = 0; e < 4; ++e) {
          int m = m0 + wm * 64 + i * 16 + rg * 4 + e;
          int b = m >> 10, s = m & 1023;
#pragma unroll
          for (int j = 0; j < 2; ++j) {
            int n_lo = n0 + wn * 64 + j * 16 + fr;
            int feat = n_lo - base;
            int h = feat >> 6, dh = feat & 63;   // dh < 32
            float a1 = acc[i][j][e]     + bias[n_lo];
            float a2 = acc[i][j + 2][e] + bias[n_lo + 32];
            float cs = ctab[s * 32 + dh], sn = stab[s * 32 + dh];
            size_t rowb = ((size_t)(b * 16 + h) * 1024 + s) * 64;
            dst[rowb + dh]      = f2b((a1 * cs - a2 * sn) * qs);
            dst[rowb + dh + 32] = f2b((a1 * sn + a2 * cs) * qs);
          }
        }
      }
    } else {
      // v tensor: TRANSPOSED store [bh][dh][s]
#pragma unroll
      for (int i = 0; i < 4; ++i) {
        int mbase = m0 + wm * 64 + i * 16 + rg * 4;
        int b = mbase >> 10, s0 = mbase & 1023;
#pragma unroll
        for (int j = 0; j < 4; ++j) {
          int n = n0 + wn * 64 + j * 16 + fr;
          int feat = n - 4096;
          int h = feat >> 6, dh = feat & 63;
          float bv = bias[n];
          union { u16 hh[4]; uint2 u2; } p;
#pragma unroll
          for (int e = 0; e < 4; ++e) p.hh[e] = f2b(acc[i][j][e] + bv);
          *(uint2*)&vtT[((size_t)(b * 16 + h) * 64 + dh) * 1024 + s0] = p.u2;
        }
      }
    }
  } else {
#pragma unroll
    for (int i = 0; i < 4; ++i)
#pragma unroll
      for (int j = 0; j < 4; ++j)
#pragma unroll
        for (int e = 0; e < 4; ++e) {
          int m = m0 + wm * 64 + i * 16 + rg * 4 + e;
          int n = n0 + wn * 64 + j * 16 + fr;
          outF[(size_t)m * N + n] = acc[i][j][e] + bias[n];
        }
  }
}

// ---------------- logL scan (base-2) ----------------
__global__ __launch_bounds__(1024) void scan_logl(
    const float* __restrict__ a, float* __restrict__ logL)
{
  __shared__ float sh[1024];
  int b = blockIdx.x, t = threadIdx.x;
  float v = (t == 0) ? 0.f : log2f(a[b * 1023 + t - 1]);
  sh[t] = v;
  __syncthreads();
  for (int off = 1; off < 1024; off <<= 1) {
    float add = (t >= off) ? sh[t - off] : 0.f;
    __syncthreads();
    sh[t] += add;
    __syncthreads();
  }
  logL[b * 1024 + t] = sh[t];
}

// ---------------- fused MFMA attention v7 ----------------
// vs r11 (88us): remove 2 of 4 barriers by (a) separate P1/P2 buffers (no K
// aliasing), (b) double-buffered V, (c) pad 72->68 so 6 buffers = 53.2KB still
// fits 3 blocks/CU. New order: LDSwrite(t); barA; [prefetch t+1 -> regs];
// QK^T; exp+Pwrite; barB; PV. barA doubles as "all prev PV done" fence.
// Reg prefetch = T14 split (r10's spill was the launch_bounds clause, absent here).
__global__ __launch_bounds__(256) void attn_fused(
    const u16* __restrict__ q1t, const u16* __restrict__ q2t,
    const u16* __restrict__ k1t, const u16* __restrict__ k2t,
    const u16* __restrict__ vtT,
    const float* __restrict__ logL, const float* __restrict__ lamp,
    float* __restrict__ ctx)
{
  __shared__ u16 K1s[64][68];
  __shared__ u16 K2s[64][68];
  __shared__ u16 P1s[64][68];
  __shared__ u16 P2s[64][68];
  __shared__ u16 Vts[2][64][68];   // V^T [dh][k], k-blocks XOR-swizzled by (dh>>3)&7
  __shared__ float lred1[2][2][32];
  __shared__ float lred2[2][2][32];

  int tid  = threadIdx.x;
  int lane = tid & 63, wave = tid >> 6;
  int wm = wave >> 1, wn = wave & 1;
  int id = blockIdx.x;
  int bh = (id & 7) * 8 + (id >> 7);        // XCD-grouped: 8 bh per XCD (L2-fit)
  int q0 = ((id >> 3) & 15) * 64;
  int b = bh >> 4;
  int fr = lane & 15, hi = lane >> 4;

  bf16x8 qf1[2][2], qf2[2][2];
#pragma unroll
  for (int i = 0; i < 2; ++i)
#pragma unroll
    for (int ks = 0; ks < 2; ++ks) {
      size_t off = ((size_t)bh * 1024 + q0 + wm * 32 + i * 16 + fr) * 64 + ks * 32 + hi * 8;
      qf1[i][ks] = *(const bf16x8*)(q1t + off);
      qf2[i][ks] = *(const bf16x8*)(q2t + off);
    }
  float Lq[2][4];
#pragma unroll
  for (int i = 0; i < 2; ++i)
#pragma unroll
    for (int r = 0; r < 4; ++r)
      Lq[i][r] = logL[b * 1024 + q0 + wm * 32 + i * 16 + hi * 4 + r];

  float lacc1[2][4], lacc2[2][4];
  f32x4 U1[2][2], U2[2][2];
#pragma unroll
  for (int i = 0; i < 2; ++i)
#pragma unroll
    for (int r = 0; r < 4; ++r) { lacc1[i][r] = 0.f; lacc2[i][r] = 0.f; }
#pragma unroll
  for (int i = 0; i < 2; ++i)
#pragma unroll
    for (int j = 0; j < 2; ++j) { U1[i][j] = 0.f; U2[i][j] = 0.f; }

  int sr = tid >> 2, sc0 = (tid & 3) * 16;
  int swz = (sr >> 3) & 7;
  int blk0 = ((sc0 >> 3) ^ swz) << 3;
  int blk1 = (((sc0 >> 3) + 1) ^ swz) << 3;

  // LDS byte addresses for packed P writes (row wm*32+hi*4, col wn*32+fr)
  unsigned a1base = (unsigned)(size_t)&P1s[wm * 32 + hi * 4][wn * 32 + fr];
  unsigned a2base = (unsigned)(size_t)&P2s[wm * 32 + hi * 4][wn * 32 + fr];

  // staging global bases (per-lane)
  const u16* kg1 = k1t + ((size_t)bh * 1024 + sr) * 64 + sc0;   // + kt*4096
  const u16* kg2 = k2t + ((size_t)bh * 1024 + sr) * 64 + sc0;
  const u16* vgT = vtT + (size_t)bh * 65536 + (size_t)sr * 1024 + sc0;  // + kt*64

  // prologue: prefetch tile 0
  bf16x8 ra0 = *(const bf16x8*)(kg1),  ra1 = *(const bf16x8*)(kg1 + 8);
  bf16x8 rb0 = *(const bf16x8*)(kg2),  rb1 = *(const bf16x8*)(kg2 + 8);
  bf16x8 rv0 = *(const bf16x8*)(vgT),  rv1 = *(const bf16x8*)(vgT + 8);

  for (int kt = 0; kt < 16; ++kt) {
    // ---- LDS write of tile kt (regs already hold it) ----
    *(bf16x8*)&K1s[sr][sc0]         = ra0;  *(bf16x8*)&K1s[sr][sc0 + 8] = ra1;
    *(bf16x8*)&K2s[sr][sc0]         = rb0;  *(bf16x8*)&K2s[sr][sc0 + 8] = rb1;
    *(bf16x8*)&Vts[kt & 1][sr][blk0] = rv0; *(bf16x8*)&Vts[kt & 1][sr][blk1] = rv1;
    float Ltl[2];
#pragma unroll
    for (int j = 0; j < 2; ++j) Ltl[j] = logL[b * 1024 + kt * 64 + wn * 32 + j * 16 + fr];
    __syncthreads();   // barA: stage visible; also fences all waves' prev PV

    // ---- prefetch tile kt+1 (latency hides under QK^T + exp) ----
    if (kt < 15) {
      size_t ko = (size_t)(kt + 1) * 4096;
      size_t vo = (size_t)(kt + 1) * 64;
      ra0 = *(const bf16x8*)(kg1 + ko);  ra1 = *(const bf16x8*)(kg1 + ko + 8);
      rb0 = *(const bf16x8*)(kg2 + ko);  rb1 = *(const bf16x8*)(kg2 + ko + 8);
      rv0 = *(const bf16x8*)(vgT + vo);  rv1 = *(const bf16x8*)(vgT + vo + 8);
    }

    // ---- QK^T ----
    f32x4 S1[2][2], S2[2][2];
#pragma unroll
    for (int i = 0; i < 2; ++i)
#pragma unroll
      for (int j = 0; j < 2; ++j) { S1[i][j] = 0.f; S2[i][j] = 0.f; }
    __builtin_amdgcn_s_setprio(1);
#pragma unroll
    for (int ks = 0; ks < 2; ++ks) {
      bf16x8 kf1[2], kf2[2];
#pragma unroll
      for (int j = 0; j < 2; ++j) {
        kf1[j] = *(const bf16x8*)&K1s[wn * 32 + j * 16 + fr][ks * 32 + hi * 8];
        kf2[j] = *(const bf16x8*)&K2s[wn * 32 + j * 16 + fr][ks * 32 + hi * 8];
      }
#pragma unroll
      for (int i = 0; i < 2; ++i)
#pragma unroll
        for (int j = 0; j < 2; ++j) {
          S1[i][j] = __builtin_amdgcn_mfma_f32_16x16x32_bf16(qf1[i][ks], kf1[j], S1[i][j], 0, 0, 0);
          S2[i][j] = __builtin_amdgcn_mfma_f32_16x16x32_bf16(qf2[i][ks], kf2[j], S2[i][j], 0, 0, 0);
        }
    }
    __builtin_amdgcn_s_setprio(0);

    // ---- exponentials (log2 domain) + packed P write ----
#pragma unroll
    for (int i = 0; i < 2; ++i) {
#pragma unroll
      for (int r = 0; r < 4; ++r) {
        float lq = Lq[i][r];
        float e1j[2], e2j[2], p1j[2], p2j[2];
#pragma unroll
        for (int j = 0; j < 2; ++j) {
          float nd = -fabsf(Ltl[j] - lq);
          float t1, t2, ec;
          asm("v_exp_f32 %0, %1" : "=v"(t1) : "v"(S1[i][j][r]));
          asm("v_exp_f32 %0, %1" : "=v"(t2) : "v"(S2[i][j][r]));
          asm("v_exp_f32 %0, %1" : "=v"(ec) : "v"(nd));
          e1j[j] = t1; e2j[j] = t2;
          p1j[j] = t1 * ec; p2j[j] = t2 * ec;
        }
        lacc1[i][r] += e1j[0] + e1j[1];
        lacc2[i][r] += e2j[0] + e2j[1];
        unsigned off = (unsigned)((i * 16 + r) * 136);
        unsigned ad1 = a1base + off, ad2 = a2base + off;
        unsigned pk1, pk2;
        asm("v_cvt_pk_bf16_f32 %0, %1, %2" : "=v"(pk1) : "v"(p1j[0]), "v"(p1j[1]));
        asm("v_cvt_pk_bf16_f32 %0, %1, %2" : "=v"(pk2) : "v"(p2j[0]), "v"(p2j[1]));
        asm volatile("ds_write_b16 %0, %1\n\tds_write_b16_d16_hi %0, %1 offset:32"
                     :: "v"(ad1), "v"(pk1) : "memory");
        asm volatile("ds_write_b16 %0, %1\n\tds_write_b16_d16_hi %0, %1 offset:32"
                     :: "v"(ad2), "v"(pk2) : "memory");
      }
    }
    __syncthreads();   // barB: P visible; also fences all waves' QK^T reads of K

    // ---- PV: U += P * V (P in P1s/P2s, V^T in Vts[kt&1]) ----
    __builtin_amdgcn_s_setprio(1);
#pragma unroll
    for (int ks = 0; ks < 2; ++ks) {
      bf16x8 pa1[2], pa2[2], vb[2];
#pragma unroll
      for (int i = 0; i < 2; ++i) {
        pa1[i] = *(const bf16x8*)&P1s[wm * 32 + i * 16 + fr][ks * 32 + hi * 8];
        pa2[i] = *(const bf16x8*)&P2s[wm * 32 + i * 16 + fr][ks * 32 + hi * 8];
      }
#pragma unroll
      for (int j = 0; j < 2; ++j) {
        int row = wn * 32 + j * 16 + fr;
        int kbb = (ks * 4 + hi) ^ ((row >> 3) & 7);
        vb[j] = *(const bf16x8*)&Vts[kt & 1][row][kbb << 3];
      }
#pragma unroll
      for (int i = 0; i < 2; ++i)
#pragma unroll
        for (int j = 0; j < 2; ++j) {
          U1[i][j] = __builtin_amdgcn_mfma_f32_16x16x32_bf16(pa1[i], vb[j], U1[i][j], 0, 0, 0);
          U2[i][j] = __builtin_amdgcn_mfma_f32_16x16x32_bf16(pa2[i], vb[j], U2[i][j], 0, 0, 0);
        }
    }
    __builtin_amdgcn_s_setprio(0);
  }

  // ---- denominator: intra-wave reduce over fr, then cross-wave over wn ----
#pragma unroll
  for (int i = 0; i < 2; ++i)
#pragma unroll
    for (int r = 0; r < 4; ++r) {
#pragma unroll
      for (int m = 1; m < 16; m <<= 1) {
        lacc1[i][r] += __shfl_xor(lacc1[i][r], m);
        lacc2[i][r] += __shfl_xor(lacc2[i][r], m);
      }
    }
  if (fr == 0) {
#pragma unroll
    for (int i = 0; i < 2; ++i)
#pragma unroll
      for (int r = 0; r < 4; ++r) {
        int rl = i * 16 + hi * 4 + r;
        lred1[wn][wm][rl] = lacc1[i][r];
        lred2[wn][wm][rl] = lacc2[i][r];
      }
  }
  __syncthreads();
  float lam = lamp[0];

  // ---- epilogue: ctx = U1/l1 - lam*U2/l2 ----
#pragma unroll
  for (int i = 0; i < 2; ++i) {
#pragma unroll
    for (int r = 0; r < 4; ++r) {
      int rl = i * 16 + hi * 4 + r;
      float l1 = lred1[0][wm][rl] + lred1[1][wm][rl];
      float l2 = lred2[0][wm][rl] + lred2[1][wm][rl];
      float inv1 = 1.f / l1;
      float inv2 = lam / l2;
      int qg = q0 + wm * 32 + i * 16 + hi * 4 + r;
#pragma unroll
      for (int j = 0; j < 2; ++j) {
        int dh = wn * 32 + j * 16 + fr;
        ctx[((size_t)bh * 1024 + qg) * 64 + dh] = U1[i][j][r] * inv1 - U2[i][j][r] * inv2;
      }
    }
  }
}

// ---------------- group norm (unchanged) ----------------
__global__ __launch_bounds__(256) void gn_stats(
    const float* __restrict__ ctx, float2* __restrict__ mv)
{
  int bh = blockIdx.x;
  const float4* p = (const float4*)(ctx + (size_t)bh * 65536);
  float s = 0.f, ss = 0.f;
  for (int i = threadIdx.x; i < 16384; i += 256) {
    float4 v = p[i];
    s  += v.x + v.y + v.z + v.w;
    ss += v.x*v.x + v.y*v.y + v.z*v.z + v.w*v.w;
  }
#pragma unroll
  for (int o = 32; o > 0; o >>= 1) { s += __shfl_down(s, o); ss += __shfl_down(ss, o); }
  __shared__ float ws0[4], ws1[4];
  int w = threadIdx.x >> 6, ln = threadIdx.x & 63;
  if (ln == 0) { ws0[w] = s; ws1[w] = ss; }
  __syncthreads();
  if (threadIdx.x == 0) {
    float S = ws0[0] + ws0[1] + ws0[2] + ws0[3];
    float SS = ws1[0] + ws1[1] + ws1[2] + ws1[3];
    float mean = S / 65536.f;
    float var = SS / 65536.f - mean * mean;
    mv[bh] = make_float2(mean, rsqrtf(var + 1e-5f));
  }
}

__global__ __launch_bounds__(256) void gn_apply(
    const float* __restrict__ ctx, const float2* __restrict__ mv,
    const float* __restrict__ gw, const float* __restrict__ gb,
    u16* __restrict__ normed)
{
  unsigned idx = blockIdx.x * 256u + threadIdx.x;
  unsigned i = idx * 4;
  unsigned d = i & 1023u;
  unsigned srow = i >> 10;
  unsigned b = srow >> 10;
  unsigned h = d >> 6, dh = d & 63u;
  float2 m = mv[b * 16 + h];
  float4 x = *(const float4*)&ctx[(((size_t)(b * 16 + h)) * 1024 + (srow & 1023u)) * 64 + dh];
  float4 g = *(const float4*)&gw[d];
  float4 be = *(const float4*)&gb[d];
  union { u16 hh[4]; uint2 u2; } p;
  p.hh[0] = f2b(((x.x - m.x) * m.y * g.x + be.x) * 0.8f);
  p.hh[1] = f2b(((x.y - m.x) * m.y * g.y + be.y) * 0.8f);
  p.hh[2] = f2b(((x.z - m.x) * m.y * g.z + be.z) * 0.8f);
  p.hh[3] = f2b(((x.w - m.x) * m.y * g.w + be.w) * 0.8f);
  *(uint2*)(normed + i) = p.u2;
}

// ---------------- launch ----------------
extern "C" void kernel_launch(void* const* d_in, const int* in_sizes, int n_in,
                              void* d_out, int out_size, void* d_ws, size_t ws_size,
                              hipStream_t stream) {
  (void)in_sizes; (void)n_in; (void)out_size; (void)ws_size;
  const float* x   = (const float*)d_in[0];
  const float* aff = (const float*)d_in[1];
  const float* Wq  = (const float*)d_in[2];
  const float* bq  = (const float*)d_in[3];
  const float* Wk  = (const float*)d_in[4];
  const float* bk  = (const float*)d_in[5];
  const float* Wv  = (const float*)d_in[6];
  const float* bv  = (const float*)d_in[7];
  const float* Wo  = (const float*)d_in[8];
  const float* bo  = (const float*)d_in[9];
  const float* gw  = (const float*)d_in[10];
  const float* gb  = (const float*)d_in[11];
  const float* lam = (const float*)d_in[12];
  float* out = (float*)d_out;

  char* w = (char*)d_ws;
  u16*    xb    = (u16*)(w);
  u16*    Wcat  = (u16*)(w + 8388608);
  u16*    Wob   = (u16*)(w + 18874368);
  float*  bcat  = (float*)(w + 20971520);
  u16*    q1t   = (u16*)(w + 20992000);
  u16*    q2t   = (u16*)(w + 29380608);
  u16*    k1t   = (u16*)(w + 37769216);
  u16*    k2t   = (u16*)(w + 46157824);
  u16*    vtT   = (u16*)(w + 54546432);   // [bh][dh][s] transposed
  float*  logL  = (float*)(w + 62935040);
  float*  ctab  = (float*)(w + 62951424);
  float*  stab  = (float*)(w + 63082496);
  float*  ctx   = (float*)(w + 63475712);
  float2* mv    = (float2*)(w + 80252928);
  u16*    normed= (u16*)(w + 80253440);

  convert_kernel<<<10245, 256, 0, stream>>>(x, Wq, Wk, Wv, Wo, bq, bk, bv, xb, Wcat, Wob, bcat);
  rope_table<<<128, 256, 0, stream>>>(ctab, stab);
  gemm_nt<0><<<dim3(40, 32), 256, 0, stream>>>(xb, Wcat, bcat, nullptr, q1t, q2t, k1t, k2t, vtT, ctab, stab, 5120);
  scan_logl<<<4, 1024, 0, stream>>>(aff, logL);
  attn_fused<<<1024, 256, 0, stream>>>(q1t, q2t, k1t, k2t, vtT, logL, lam, ctx);
  gn_stats<<<64, 256, 0, stream>>>(ctx, mv);
  gn_apply<<<4096, 256, 0, stream>>>(ctx, mv, gw, gb, normed);
  gemm_nt<1><<<dim3(8, 32), 256, 0, stream>>>(normed, Wob, bo, out, nullptr, nullptr, nullptr, nullptr, nullptr, ctab, stab, 1024);
}